// Round 3
// baseline (15558.914 us; speedup 1.0000x reference)
//
#include <hip/hip_runtime.h>
#include <math.h>

namespace {

constexpr int Bn = 64, Ln = 256, Cn = 8, Dn = 512, Mn = 512;
constexpr int TWO_M = 2 * Mn;        // 1024
constexpr int PCOLS = 2048;          // 1536 iou (+both biases) | 512 fx (+b_fx)
constexpr size_t P_FLOATS = (size_t)Bn * Ln * PCOLS;   // 33,554,432
constexpr size_t P_BYTES  = P_FLOATS * 4;              // 128 MB

__device__ __forceinline__ float sigmoidf_(float v) { return 1.0f / (1.0f + __expf(-v)); }
__device__ __forceinline__ float dot4_(float4 a, float4 b) {
    return a.x * b.x + a.y * b.y + a.z * b.z + a.w * b.w;
}

// ============================================================================
// Precompute kernel: P[r][0:1536] = x_r @ W_ioux.T + b_ioux + b_iouh
//                    P[r][1536:2048] = x_r @ W_fx.T + b_fx     (r = b*Ln + t)
// ============================================================================
constexpr int GM = 128, GN = 64, GK = 32, GLD = 36;

__global__ __launch_bounds__(256, 4)
void proj_kernel(const float* __restrict__ x,
                 const float* __restrict__ W_ioux, const float* __restrict__ b_ioux,
                 const float* __restrict__ b_iouh,
                 const float* __restrict__ W_fx, const float* __restrict__ b_fx,
                 float* __restrict__ P)
{
    __shared__ float sX[GM * GLD];
    __shared__ float sW[GN * GLD];
    const int tid = threadIdx.x;
    const int rb = blockIdx.x >> 5;       // 0..127
    const int cb = blockIdx.x & 31;       // 0..31
    const int r0 = rb * GM, c0 = cb * GN;
    const bool is_iou = (c0 < 3 * Mn);
    const int rgrp = tid >> 4, cgrp = tid & 15;

    float acc[8][4];
    #pragma unroll
    for (int r = 0; r < 8; ++r)
        #pragma unroll
        for (int c = 0; c < 4; ++c) acc[r][c] = 0.f;

    for (int k0 = 0; k0 < Dn; k0 += GK) {
        #pragma unroll
        for (int i = 0; i < 4; ++i) {
            int flat = i * 256 + tid;
            int row = flat >> 3, kk = flat & 7;
            *(float4*)&sX[row * GLD + kk * 4] =
                *(const float4*)&x[(size_t)(r0 + row) * Dn + k0 + kk * 4];
        }
        #pragma unroll
        for (int i = 0; i < 2; ++i) {
            int flat = i * 256 + tid;
            int row = flat >> 3, kk = flat & 7;
            const float* wsrc = is_iou ? &W_ioux[(size_t)(c0 + row) * Dn]
                                       : &W_fx[(size_t)(c0 - 3 * Mn + row) * Dn];
            *(float4*)&sW[row * GLD + kk * 4] = *(const float4*)&wsrc[k0 + kk * 4];
        }
        __syncthreads();
        #pragma unroll
        for (int k4 = 0; k4 < 8; ++k4) {
            float4 xv[8], wv[4];
            #pragma unroll
            for (int r = 0; r < 8; ++r) xv[r] = *(const float4*)&sX[(rgrp + r * 16) * GLD + k4 * 4];
            #pragma unroll
            for (int c = 0; c < 4; ++c) wv[c] = *(const float4*)&sW[(cgrp + c * 16) * GLD + k4 * 4];
            #pragma unroll
            for (int r = 0; r < 8; ++r)
                #pragma unroll
                for (int c = 0; c < 4; ++c) acc[r][c] += dot4_(xv[r], wv[c]);
        }
        __syncthreads();
    }
    #pragma unroll
    for (int c = 0; c < 4; ++c) {
        int col = c0 + cgrp + c * 16;
        float bias = is_iou ? (b_ioux[col] + b_iouh[col]) : b_fx[col - 3 * Mn];
        #pragma unroll
        for (int r = 0; r < 8; ++r) {
            int row = r0 + rgrp + r * 16;
            P[(size_t)row * PCOLS + col] = acc[r][c] + bias;
        }
    }
}

// ============================================================================
// Persistent cooperative kernel: 256 blocks = 8 groups x 32 m-blocks.
// Group g owns batches g*8..g*8+7; block handles cols m0..m0+15 of each gate.
// All 255 steps in one launch; per-group 32-block atomic barrier per step.
// Weights held in VGPRs for the whole kernel (immune to L2 invalidations).
// ============================================================================
// LDS carve (floats)
constexpr int PS_CH  = 0;                  // gathered c_h: 64 rows x 512
constexpr int PS_HS  = PS_CH + 64 * 512;   // h_sum: 8 x 512
constexpr int PS_FD  = PS_HS + 8 * 512;    // f-matmul out: 64 x 16
constexpr int PS_IOU = PS_FD + 64 * 16;    // iou_h: 8 x 48
constexpr int PS_CS  = PS_IOU + 8 * 48;    // gathered c_s (own cols): 64 x 16
constexpr int PS_XMC = PS_CS + 64 * 16;    // 64
constexpr int PS_XM  = PS_XMC + 64;        // 8
constexpr int PS_XC  = PS_XM + 8;          // 64 (ints)
constexpr int PS_FLOATS = PS_XC + 64;      // 39432
constexpr size_t PS_BYTES = (size_t)PS_FLOATS * 4;   // 157,728 B
static_assert(PS_BYTES <= 163840, "persist LDS over budget");

__global__ __launch_bounds__(512, 2)
void persist_kernel(const int* __restrict__ x_c, const float* __restrict__ x_m,
                    const float* __restrict__ x_m_c,
                    const float* __restrict__ W_iouh, const float* __restrict__ W_fh,
                    const float* __restrict__ b_fh, const float* __restrict__ P,
                    float* __restrict__ out, unsigned* __restrict__ ctr)
{
    extern __shared__ float lds[];
    float* s_ch  = lds + PS_CH;
    float* s_hs  = lds + PS_HS;
    float* s_fd  = lds + PS_FD;
    float* s_iou = lds + PS_IOU;
    float* s_cs  = lds + PS_CS;
    float* s_xmc = lds + PS_XMC;
    float* s_xm  = lds + PS_XM;
    int*   s_xc  = (int*)(lds + PS_XC);

    const int tid = threadIdx.x;
    const int mt = blockIdx.x & 31;
    const int g  = blockIdx.x >> 5;
    const int m0 = mt * 16;
    const int b0 = g * 8;
    unsigned* myctr = ctr + g * 32;   // 128B-separated counters

    // ---- G2 weight registers: W_fh slice, thread (rq, j4, ks32) ----
    // k-set per thread: {ks32*4 + i4*128 + 0..3}, cols j4*4..j4*4+3
    const int ks32 = tid & 31, j4 = (tid >> 5) & 3, rq = tid >> 7;
    float4 w2[4][4];
    #pragma unroll
    for (int jj = 0; jj < 4; ++jj)
        #pragma unroll
        for (int i4 = 0; i4 < 4; ++i4)
            w2[jj][i4] = *(const float4*)&W_fh[(size_t)(m0 + j4 * 4 + jj) * Dn
                                               + ks32 * 4 + i4 * 128];

    // ---- G1 weight registers: W_iouh slice, thread (c8, ks64), threads<384 ----
    // cols c48 = c8*8..+7 (c48 = s*16+j), k-set {ks64*4 + i4*256 + 0..3}
    const int ks64 = tid & 63, c8 = tid >> 6;
    float4 w1[8][2];
    if (c8 < 6) {
        #pragma unroll
        for (int cc = 0; cc < 8; ++cc) {
            const int c48 = c8 * 8 + cc, s = c48 >> 4, j = c48 & 15;
            #pragma unroll
            for (int i4 = 0; i4 < 2; ++i4)
                w1[cc][i4] = *(const float4*)&W_iouh[(size_t)(s * Mn + m0 + j) * Mn
                                                     + ks64 * 4 + i4 * 256];
        }
    }
    const float bfh_j = b_fh[m0 + (tid & 15)];   // used by gates threads (<128)

    for (int t = 1; t < Ln; ++t) {
        // ---- per-step scalars ----
        if (tid < 64) {
            const int b = tid >> 3, c = tid & 7;
            s_xc[tid]  = x_c[((size_t)(b0 + b) * Ln + t) * Cn + c];
            s_xmc[tid] = x_m_c[((size_t)(b0 + b) * Ln + t) * Cn + c];
        } else if (tid < 72) {
            s_xm[tid - 64] = x_m[(size_t)(b0 + tid - 64) * Ln + t];
        }
        __syncthreads();

        // ---- gather c_h into LDS + fused child_h_sum; thread (b, kslot) ----
        {
            const int b = tid >> 6, kslot = tid & 63;
            #pragma unroll
            for (int i = 0; i < 2; ++i) {
                const int k = kslot * 4 + i * 256;
                float4 hs = make_float4(0.f, 0.f, 0.f, 0.f);
                #pragma unroll
                for (int c = 0; c < 8; ++c) {
                    const int idx = s_xc[b * 8 + c];
                    float4 v = make_float4(0.f, 0.f, 0.f, 0.f);
                    if (idx < t)
                        v = *(const float4*)&out[((size_t)(b0 + b) * Ln + idx) * TWO_M + Mn + k];
                    *(float4*)&s_ch[(b * 8 + c) * 512 + k] = v;
                    const float w = s_xmc[b * 8 + c];
                    hs.x += w * v.x; hs.y += w * v.y; hs.z += w * v.z; hs.w += w * v.w;
                }
                *(float4*)&s_hs[b * 512 + k] = hs;
            }
        }
        // ---- gather c_s (own 16 cols); threads<256: (row, quad) ----
        if (tid < 256) {
            const int row = tid >> 2, q = tid & 3;
            const int idx = s_xc[row];
            float4 v = make_float4(0.f, 0.f, 0.f, 0.f);
            if (idx < t)
                v = *(const float4*)&out[((size_t)(b0 + (row >> 3)) * Ln + idx) * TWO_M
                                         + m0 + q * 4];
            *(float4*)&s_cs[row * 16 + q * 4] = v;
        }
        __syncthreads();

        // ---- G2: c_h(64 x 512) @ W_fh_slice.T(16) ----
        {
            float acc2[16][4];
            #pragma unroll
            for (int rr = 0; rr < 16; ++rr)
                #pragma unroll
                for (int jj = 0; jj < 4; ++jj) acc2[rr][jj] = 0.f;
            #pragma unroll
            for (int rr = 0; rr < 16; ++rr) {
                const int r = rq * 16 + rr;
                #pragma unroll
                for (int i4 = 0; i4 < 4; ++i4) {
                    const float4 ch = *(const float4*)&s_ch[r * 512 + ks32 * 4 + i4 * 128];
                    #pragma unroll
                    for (int jj = 0; jj < 4; ++jj) acc2[rr][jj] += dot4_(ch, w2[jj][i4]);
                }
            }
            #pragma unroll
            for (int rr = 0; rr < 16; ++rr)
                #pragma unroll
                for (int jj = 0; jj < 4; ++jj) {
                    float v = acc2[rr][jj];
                    v += __shfl_xor(v, 1);  v += __shfl_xor(v, 2);
                    v += __shfl_xor(v, 4);  v += __shfl_xor(v, 8);
                    v += __shfl_xor(v, 16);
                    acc2[rr][jj] = v;
                }
            if (ks32 == 0) {
                #pragma unroll
                for (int rr = 0; rr < 16; ++rr)
                    *(float4*)&s_fd[(rq * 16 + rr) * 16 + j4 * 4] =
                        make_float4(acc2[rr][0], acc2[rr][1], acc2[rr][2], acc2[rr][3]);
            }
        }

        // ---- G1: h_sum(8 x 512) @ W_iouh_slice.T(48); threads<384 ----
        if (c8 < 6) {
            float acc1[8][8];
            #pragma unroll
            for (int b = 0; b < 8; ++b)
                #pragma unroll
                for (int cc = 0; cc < 8; ++cc) acc1[b][cc] = 0.f;
            #pragma unroll
            for (int i4 = 0; i4 < 2; ++i4)
                #pragma unroll
                for (int b = 0; b < 8; ++b) {
                    const float4 h = *(const float4*)&s_hs[b * 512 + ks64 * 4 + i4 * 256];
                    #pragma unroll
                    for (int cc = 0; cc < 8; ++cc) acc1[b][cc] += dot4_(h, w1[cc][i4]);
                }
            #pragma unroll
            for (int b = 0; b < 8; ++b)
                #pragma unroll
                for (int cc = 0; cc < 8; ++cc) {
                    float v = acc1[b][cc];
                    v += __shfl_xor(v, 1);  v += __shfl_xor(v, 2);
                    v += __shfl_xor(v, 4);  v += __shfl_xor(v, 8);
                    v += __shfl_xor(v, 16); v += __shfl_xor(v, 32);
                    acc1[b][cc] = v;
                }
            if (ks64 == 0) {
                #pragma unroll
                for (int b = 0; b < 8; ++b) {
                    *(float4*)&s_iou[b * 48 + c8 * 8] =
                        make_float4(acc1[b][0], acc1[b][1], acc1[b][2], acc1[b][3]);
                    *(float4*)&s_iou[b * 48 + c8 * 8 + 4] =
                        make_float4(acc1[b][4], acc1[b][5], acc1[b][6], acc1[b][7]);
                }
            }
        }
        __syncthreads();

        // ---- gates, c/h, mask-blend, store (threads<128: (b, j)) ----
        if (tid < 128) {
            const int b = tid >> 4, j = tid & 15;
            const size_t prow = ((size_t)(b0 + b) * Ln + t) * (size_t)PCOLS;
            const float iv  = s_iou[b * 48 + 0 * 16 + j] + P[prow + 0 * Mn + m0 + j];
            const float ov  = s_iou[b * 48 + 1 * 16 + j] + P[prow + 1 * Mn + m0 + j];
            const float uv  = s_iou[b * 48 + 2 * 16 + j] + P[prow + 2 * Mn + m0 + j];
            const float fxv =                              P[prow + 3 * Mn + m0 + j];
            const float i_ = sigmoidf_(iv);
            const float o_ = sigmoidf_(ov);
            const float u_ = tanhf(uv);
            float facc = 0.f;
            #pragma unroll
            for (int c = 0; c < 8; ++c) {
                const int row = b * 8 + c;
                const float f = sigmoidf_(s_fd[row * 16 + j] + bfh_j + fxv);
                facc += f * s_cs[row * 16 + j] * s_xmc[row];
            }
            const float cv = i_ * u_ + facc;
            const float hv = o_ * tanhf(cv);
            const float mv = s_xm[b];
            const size_t ob = ((size_t)(b0 + b) * Ln + t) * TWO_M;
            const size_t pb = ((size_t)(b0 + b) * Ln + (t - 1)) * TWO_M;
            out[ob + m0 + j]      = mv * cv + (1.f - mv) * out[pb + m0 + j];
            out[ob + Mn + m0 + j] = mv * hv + (1.f - mv) * out[pb + Mn + m0 + j];
        }

        // ---- group barrier (release writes, acquire before next gather) ----
        __syncthreads();
        if (t < Ln - 1) {
            if (tid == 0) {
                __hip_atomic_fetch_add(myctr, 1u, __ATOMIC_RELEASE, __HIP_MEMORY_SCOPE_AGENT);
                const unsigned target = 32u * (unsigned)t;
                while (__hip_atomic_load(myctr, __ATOMIC_RELAXED, __HIP_MEMORY_SCOPE_AGENT) < target)
                    __builtin_amdgcn_s_sleep(2);
                (void)__hip_atomic_load(myctr, __ATOMIC_ACQUIRE, __HIP_MEMORY_SCOPE_AGENT);
            }
            __syncthreads();
        }
    }
}

// ============================================================================
// Legacy monolithic step kernel (fallback when ws is too small for P)
// ============================================================================
constexpr int LBT = 4, LMT = 32, LNMT = Mn / LMT, LPAD = 4, LDK = Dn + LPAD;
constexpr int L_U16 = 4096, L_CHS = LBT * LDK, L_CH = LBT * Cn * LDK,
              L_WFH = LMT * LDK, L_CS = LBT * Cn * LMT, L_IOUF = 4 * LBT * LMT;
constexpr int L_FLOATS = L_U16 + L_CHS + L_CH + L_WFH + L_CS + L_IOUF + 32 + 4 + 32;
constexpr size_t L_BYTES = (size_t)L_FLOATS * 4;

__global__ __launch_bounds__(256, 1)
void step_legacy(const float* __restrict__ x, const int* __restrict__ x_c,
                 const float* __restrict__ x_m, const float* __restrict__ x_m_c,
                 const float* __restrict__ W_ioux, const float* __restrict__ b_ioux,
                 const float* __restrict__ W_iouh, const float* __restrict__ b_iouh,
                 const float* __restrict__ W_fx, const float* __restrict__ b_fx,
                 const float* __restrict__ W_fh, const float* __restrict__ b_fh,
                 float* __restrict__ out, int t)
{
    extern __shared__ float lds[];
    float* u16    = lds;
    float* s_chs  = u16 + L_U16;
    float* s_ch   = s_chs + L_CHS;
    float* s_wfh  = s_ch + L_CH;
    float* s_cs   = s_wfh + L_WFH;
    float* s_iouf = s_cs + L_CS;
    float* s_xmc  = s_iouf + L_IOUF;
    float* s_xm   = s_xmc + 32;
    int*   s_xc   = (int*)(s_xm + 4);

    const int tid = threadIdx.x;
    const int mt = blockIdx.x & (LNMT - 1);
    const int bt = blockIdx.x >> 4;
    const int b0 = bt * LBT, m0 = mt * LMT;

    #pragma unroll
    for (int i = 0; i < 8; ++i) {
        int flat = i * 256 + tid, b = flat >> 9, k = flat & 511;
        u16[b * LDK + k] = x[((size_t)(b0 + b) * Ln + t) * Dn + k];
    }
    if (tid < 32) {
        int b = tid >> 3, c = tid & 7;
        s_xc[tid]  = x_c[((size_t)(b0 + b) * Ln + t) * Cn + c];
        s_xmc[tid] = x_m_c[((size_t)(b0 + b) * Ln + t) * Cn + c];
    }
    if (tid < 4) s_xm[tid] = x_m[(size_t)(b0 + tid) * Ln + t];
    for (int i = 0; i < 64; ++i) {
        int flat = i * 256 + tid, j = flat >> 9, k = flat & 511;
        s_wfh[j * LDK + k] = W_fh[(size_t)(m0 + j) * Dn + k];
    }
    __syncthreads();

    #pragma unroll
    for (int i = 0; i < 8; ++i) {
        int flat = i * 256 + tid, b = flat >> 9, k = flat & 511;
        float acc = 0.f;
        #pragma unroll
        for (int c = 0; c < 8; ++c) {
            int idx = s_xc[b * 8 + c];
            float v = 0.f;
            if (idx < t) v = out[((size_t)(b0 + b) * Ln + idx) * TWO_M + Mn + k];
            s_ch[(b * 8 + c) * LDK + k] = v;
            acc += s_xmc[b * 8 + c] * v;
        }
        s_chs[b * LDK + k] = acc;
    }
    #pragma unroll
    for (int i = 0; i < 4; ++i) {
        int flat = i * 256 + tid;
        int b = flat >> 8, rem = flat & 255, c = rem >> 5, j = rem & 31;
        int idx = s_xc[b * 8 + c];
        float v = 0.f;
        if (idx < t) v = out[((size_t)(b0 + b) * Ln + idx) * TWO_M + m0 + j];
        s_cs[flat] = v;
    }
    __syncthreads();

    {
        const int unit = tid >> 3, ksl = tid & 7, s = unit >> 3, jg = unit & 7;
        float acc[4][4];
        #pragma unroll
        for (int b = 0; b < 4; ++b)
            #pragma unroll
            for (int jj = 0; jj < 4; ++jj) acc[b][jj] = 0.f;
        if (s < 3) {
            const int colbase = s * Mn + m0 + jg * 4;
            #pragma unroll 4
            for (int it = 0; it < 16; ++it) {
                const int k = it * 32 + ksl * 4;
                float4 sx[4], sc[4];
                #pragma unroll
                for (int b = 0; b < 4; ++b) {
                    sx[b] = *(const float4*)&u16[b * LDK + k];
                    sc[b] = *(const float4*)&s_chs[b * LDK + k];
                }
                #pragma unroll
                for (int jj = 0; jj < 4; ++jj) {
                    const float4 wx = *(const float4*)&W_ioux[(size_t)(colbase + jj) * Dn + k];
                    const float4 wh = *(const float4*)&W_iouh[(size_t)(colbase + jj) * Dn + k];
                    #pragma unroll
                    for (int b = 0; b < 4; ++b)
                        acc[b][jj] += dot4_(sx[b], wx) + dot4_(sc[b], wh);
                }
            }
        } else {
            const int colbase = m0 + jg * 4;
            #pragma unroll 4
            for (int it = 0; it < 16; ++it) {
                const int k = it * 32 + ksl * 4;
                float4 sx[4];
                #pragma unroll
                for (int b = 0; b < 4; ++b) sx[b] = *(const float4*)&u16[b * LDK + k];
                #pragma unroll
                for (int jj = 0; jj < 4; ++jj) {
                    const float4 wx = *(const float4*)&W_fx[(size_t)(colbase + jj) * Dn + k];
                    #pragma unroll
                    for (int b = 0; b < 4; ++b) acc[b][jj] += dot4_(sx[b], wx);
                }
            }
        }
        __syncthreads();
        #pragma unroll
        for (int b = 0; b < 4; ++b)
            #pragma unroll
            for (int jj = 0; jj < 4; ++jj)
                u16[unit * 128 + ksl * 16 + b * 4 + jj] = acc[b][jj];
        __syncthreads();
        #pragma unroll
        for (int e = 0; e < 2; ++e) {
            const int task = e * 256 + tid;
            const int unit2 = task >> 4, rem = task & 15;
            float v = 0.f;
            #pragma unroll
            for (int k2 = 0; k2 < 8; ++k2) v += u16[unit2 * 128 + k2 * 16 + rem];
            const int s2 = unit2 >> 3, jg2 = unit2 & 7;
            const int bb = rem >> 2, jj = rem & 3, j = jg2 * 4 + jj;
            float bias = (s2 < 3) ? (b_ioux[s2 * Mn + m0 + j] + b_iouh[s2 * Mn + m0 + j])
                                  : b_fx[m0 + j];
            s_iouf[(s2 * 4 + bb) * 32 + j] = v + bias;
        }
    }
    __syncthreads();

    {
        const int pos = tid >> 2, ksc = tid & 3, rg = pos >> 3, jg = pos & 7;
        float acc[4][4];
        #pragma unroll
        for (int r = 0; r < 4; ++r)
            #pragma unroll
            for (int j = 0; j < 4; ++j) acc[r][j] = 0.f;
        #pragma unroll 4
        for (int it = 0; it < 32; ++it) {
            const int k = it * 16 + ksc * 4;
            float4 ch[4], wf[4];
            #pragma unroll
            for (int r = 0; r < 4; ++r) ch[r] = *(const float4*)&s_ch[(rg * 4 + r) * LDK + k];
            #pragma unroll
            for (int j = 0; j < 4; ++j) wf[j] = *(const float4*)&s_wfh[(jg * 4 + j) * LDK + k];
            #pragma unroll
            for (int r = 0; r < 4; ++r)
                #pragma unroll
                for (int j = 0; j < 4; ++j) acc[r][j] += dot4_(ch[r], wf[j]);
        }
        #pragma unroll
        for (int r = 0; r < 4; ++r)
            #pragma unroll
            for (int j = 0; j < 4; ++j)
                u16[((rg * 4 + r) * 32 + (jg * 4 + j)) * 4 + ksc] = acc[r][j];
    }
    __syncthreads();

    if (tid < 128) {
        const int b = tid >> 5, j = tid & 31;
        const float iv  = s_iouf[(0 * 4 + b) * 32 + j];
        const float ov  = s_iouf[(1 * 4 + b) * 32 + j];
        const float uv  = s_iouf[(2 * 4 + b) * 32 + j];
        const float fxv = s_iouf[(3 * 4 + b) * 32 + j];
        const float i_ = sigmoidf_(iv), o_ = sigmoidf_(ov), u_ = tanhf(uv);
        const float bfh = b_fh[m0 + j];
        float facc = 0.f;
        #pragma unroll
        for (int c = 0; c < 8; ++c) {
            const int row = b * 8 + c;
            const float fd = u16[(row * 32 + j) * 4 + 0] + u16[(row * 32 + j) * 4 + 1]
                           + u16[(row * 32 + j) * 4 + 2] + u16[(row * 32 + j) * 4 + 3];
            const float f = sigmoidf_(fd + bfh + fxv);
            facc += f * s_cs[row * 32 + j] * s_xmc[row];
        }
        const float cval = i_ * u_ + facc;
        const float hval = o_ * tanhf(cval);
        const float mval = s_xm[b];
        const size_t base  = ((size_t)(b0 + b) * Ln + t) * TWO_M;
        const size_t pbase = ((size_t)(b0 + b) * Ln + (t - 1)) * TWO_M;
        out[base + m0 + j]      = mval * cval + (1.f - mval) * out[pbase + m0 + j];
        out[base + Mn + m0 + j] = mval * hval + (1.f - mval) * out[pbase + Mn + m0 + j];
    }
}

__global__ void zero_row0(float* __restrict__ out) {
    int i = blockIdx.x * 256 + threadIdx.x;
    int b = i >> 10, j = i & 1023;
    out[(size_t)b * Ln * TWO_M + j] = 0.f;
}

__global__ void zero_ctr(unsigned* __restrict__ c) {
    if (threadIdx.x < 8) c[threadIdx.x * 32] = 0u;
}

__global__ void final_copy(const float* __restrict__ out, float* __restrict__ fin) {
    int i = blockIdx.x * 256 + threadIdx.x;
    int b = i >> 10, j = i & 1023;
    fin[i] = out[((size_t)b * Ln + (Ln - 1)) * TWO_M + j];
}

} // namespace

extern "C" void kernel_launch(void* const* d_in, const int* in_sizes, int n_in,
                              void* d_out, int out_size, void* d_ws, size_t ws_size,
                              hipStream_t stream) {
    (void)in_sizes; (void)n_in; (void)out_size;
    const float* x      = (const float*)d_in[0];
    const int*   x_c    = (const int*)d_in[1];
    const float* x_m    = (const float*)d_in[2];
    const float* x_m_c  = (const float*)d_in[3];
    const float* W_ioux = (const float*)d_in[4];
    const float* b_ioux = (const float*)d_in[5];
    const float* W_iouh = (const float*)d_in[6];
    const float* b_iouh = (const float*)d_in[7];
    const float* W_fx   = (const float*)d_in[8];
    const float* b_fx   = (const float*)d_in[9];
    const float* W_fh   = (const float*)d_in[10];
    const float* b_fh   = (const float*)d_in[11];
    float* out = (float*)d_out;
    float* fin = out + (size_t)Bn * Ln * TWO_M;

    hipFuncSetAttribute((const void*)persist_kernel,
                        hipFuncAttributeMaxDynamicSharedMemorySize, (int)PS_BYTES);
    hipFuncSetAttribute((const void*)step_legacy,
                        hipFuncAttributeMaxDynamicSharedMemorySize, (int)L_BYTES);

    hipLaunchKernelGGL(zero_row0, dim3(256), dim3(256), 0, stream, out);

    if (ws_size >= P_BYTES) {
        float* Pp = (float*)d_ws;
        // barrier counters live inside P row (b=0,t=0), which no step reads.
        unsigned* ctr = (unsigned*)d_ws;
        hipLaunchKernelGGL(proj_kernel, dim3(4096), dim3(256), 0, stream,
                           x, W_ioux, b_ioux, b_iouh, W_fx, b_fx, Pp);
        hipLaunchKernelGGL(zero_ctr, dim3(1), dim3(64), 0, stream, ctr);
        void* kargs[] = { (void*)&x_c, (void*)&x_m, (void*)&x_m_c, (void*)&W_iouh,
                          (void*)&W_fh, (void*)&b_fh, (void*)&Pp, (void*)&out,
                          (void*)&ctr };
        hipLaunchCooperativeKernel((const void*)persist_kernel, dim3(256), dim3(512),
                                   kargs, (unsigned)PS_BYTES, stream);
    } else {
        for (int t = 1; t < Ln; ++t) {
            hipLaunchKernelGGL(step_legacy, dim3(256), dim3(256), L_BYTES, stream,
                               x, x_c, x_m, x_m_c, W_ioux, b_ioux, W_iouh, b_iouh,
                               W_fx, b_fx, W_fh, b_fh, out, t);
        }
    }
    hipLaunchKernelGGL(final_copy, dim3(256), dim3(256), 0, stream, out, fin);
}

// Round 4
// 14752.528 us; speedup vs baseline: 1.0547x; 1.0547x over previous
//
#include <hip/hip_runtime.h>
#include <math.h>

namespace {

constexpr int Bn = 64, Ln = 256, Cn = 8, Dn = 512, Mn = 512;
constexpr int TWO_M = 2 * Mn;        // 1024
constexpr int PCOLS = 2048;          // 1536 iou (+both biases) | 512 fx (+b_fx)
constexpr size_t P_FLOATS = (size_t)Bn * Ln * PCOLS;   // 33,554,432
constexpr size_t P_BYTES  = P_FLOATS * 4;              // 128 MB

__device__ __forceinline__ float sigmoidf_(float v) { return 1.0f / (1.0f + __expf(-v)); }
__device__ __forceinline__ float dot4_(float4 a, float4 b) {
    return a.x * b.x + a.y * b.y + a.z * b.z + a.w * b.w;
}

// ============================================================================
// proj2: P[r][0:1536] = x_r @ W_ioux.T + b_ioux + b_iouh
//        P[r][1536:2048] = x_r @ W_fx.T + b_fx        (r = b*Ln + t)
// 64x64 tile, 256 thr, 4x4 per thread, K-chunk 32, pad-36 LDS (conflict-free).
// ============================================================================
constexpr int PJLD = 36;

__global__ __launch_bounds__(256)
void proj2_kernel(const float* __restrict__ x,
                  const float* __restrict__ W_ioux, const float* __restrict__ b_ioux,
                  const float* __restrict__ b_iouh,
                  const float* __restrict__ W_fx, const float* __restrict__ b_fx,
                  float* __restrict__ P)
{
    __shared__ float sA[64 * PJLD];
    __shared__ float sB[64 * PJLD];
    const int tid = threadIdx.x;
    const int rb = blockIdx.x >> 5;       // 0..255
    const int cb = blockIdx.x & 31;       // 0..31
    const int r0 = rb * 64, c0 = cb * 64;
    const bool is_iou = (c0 < 3 * Mn);
    const int ri = tid & 15, ci = tid >> 4;

    float acc[4][4];
    #pragma unroll
    for (int r = 0; r < 4; ++r)
        #pragma unroll
        for (int c = 0; c < 4; ++c) acc[r][c] = 0.f;

    for (int k0 = 0; k0 < Dn; k0 += 32) {
        #pragma unroll
        for (int i = 0; i < 2; ++i) {
            const int flat = i * 256 + tid;           // 0..511
            const int row = flat >> 3, kq = flat & 7;
            *(float4*)&sA[row * PJLD + kq * 4] =
                *(const float4*)&x[(size_t)(r0 + row) * Dn + k0 + kq * 4];
            const float* wsrc = is_iou ? &W_ioux[(size_t)(c0 + row) * Dn]
                                       : &W_fx[(size_t)(c0 - 3 * Mn + row) * Dn];
            *(float4*)&sB[row * PJLD + kq * 4] = *(const float4*)&wsrc[k0 + kq * 4];
        }
        __syncthreads();
        #pragma unroll
        for (int k4 = 0; k4 < 8; ++k4) {
            float4 av[4], bv[4];
            #pragma unroll
            for (int r = 0; r < 4; ++r) av[r] = *(const float4*)&sA[(ri + r * 16) * PJLD + k4 * 4];
            #pragma unroll
            for (int c = 0; c < 4; ++c) bv[c] = *(const float4*)&sB[(ci + c * 16) * PJLD + k4 * 4];
            #pragma unroll
            for (int r = 0; r < 4; ++r)
                #pragma unroll
                for (int c = 0; c < 4; ++c) acc[r][c] += dot4_(av[r], bv[c]);
        }
        __syncthreads();
    }
    #pragma unroll
    for (int c = 0; c < 4; ++c) {
        const int col = c0 + ci + c * 16;
        const float bias = is_iou ? (b_ioux[col] + b_iouh[col]) : b_fx[col - 3 * Mn];
        #pragma unroll
        for (int r = 0; r < 4; ++r)
            P[(size_t)(r0 + ri + r * 16) * PCOLS + col] = acc[r][c] + bias;
    }
}

// ============================================================================
// persist2: 256 blocks = 8 groups x 32 m-blocks, XCD-co-located via g = bid&7.
// All gathers read global directly (XCD-L2-hot); LDS only for small shared
// state (28 KB static). Weights live in registers for the whole kernel.
// ============================================================================
__global__ __launch_bounds__(512, 2)
void persist2_kernel(const int* __restrict__ x_c, const float* __restrict__ x_m,
                     const float* __restrict__ x_m_c,
                     const float* __restrict__ W_iouh, const float* __restrict__ W_fh,
                     const float* __restrict__ b_fh, const float* __restrict__ P,
                     float* __restrict__ out, unsigned* __restrict__ ctr)
{
    __shared__ float s_hs[8 * 512];    // child_h_sum per batch
    __shared__ float s_fd[64 * 16];    // G2 out (c_h @ W_fh.T slice)
    __shared__ float s_iou[8 * 48];    // G1 out (h_sum @ W_iouh.T slice)
    __shared__ float s_cs[64 * 16];    // gathered c_s (own cols)
    __shared__ float s_prev[8 * 32];   // prev step's blended c|h (own cols)
    __shared__ float s_xmc[64];
    __shared__ float s_xm[8];
    __shared__ int   s_xc[64];

    const int tid = threadIdx.x;
    const int g  = blockIdx.x & 7;        // XCD co-location: group varies fastest
    const int mt = blockIdx.x >> 3;       // 0..31
    const int m0 = mt * 16;
    const int b0 = g * 8;
    unsigned* myctr = ctr + g * 32;       // 128B-separated counters

    // ---- G2 weights in regs: thread (rq, j4, ks32) ----
    const int ks32 = tid & 31, j4 = (tid >> 5) & 3, rq = tid >> 7;
    float4 w2[4][4];                      // [jj][i4]
    #pragma unroll
    for (int jj = 0; jj < 4; ++jj)
        #pragma unroll
        for (int i4 = 0; i4 < 4; ++i4)
            w2[jj][i4] = *(const float4*)&W_fh[(size_t)(m0 + j4 * 4 + jj) * Dn
                                               + ks32 * 4 + i4 * 128];

    // ---- G1 weights in regs: thread (c8, ks64), waves 0..5 ----
    const int ks64 = tid & 63, c8 = tid >> 6;
    float4 w1[8][2];
    if (c8 < 6) {
        #pragma unroll
        for (int cc = 0; cc < 8; ++cc) {
            const int c48 = c8 * 8 + cc, s = c48 >> 4, j = c48 & 15;
            #pragma unroll
            for (int i4 = 0; i4 < 2; ++i4)
                w1[cc][i4] = *(const float4*)&W_iouh[(size_t)(s * Mn + m0 + j) * Mn
                                                     + ks64 * 4 + i4 * 256];
        }
    }
    const float bfh_j = b_fh[m0 + (tid & 15)];
    if (tid < 256) s_prev[tid] = 0.f;     // prev0 = zeros (covers 8*32)

    for (int t = 1; t < Ln; ++t) {
        // ---- early P prefetch (L3-latency hidden under the whole step) ----
        float p0 = 0.f, p1 = 0.f, p2 = 0.f, p3 = 0.f;
        if (tid < 128) {
            const size_t prow = ((size_t)(b0 + (tid >> 4)) * Ln + t) * (size_t)PCOLS
                                + m0 + (tid & 15);
            p0 = P[prow];           p1 = P[prow + Mn];
            p2 = P[prow + 2 * Mn];  p3 = P[prow + 3 * Mn];
        }
        // ---- per-step scalars ----
        if (tid < 64) {
            const int b = tid >> 3, c = tid & 7;
            s_xc[tid]  = x_c[((size_t)(b0 + b) * Ln + t) * Cn + c];
            s_xmc[tid] = x_m_c[((size_t)(b0 + b) * Ln + t) * Cn + c];
        } else if (tid < 72) {
            s_xm[tid - 64] = x_m[(size_t)(b0 + tid - 64) * Ln + t];
        }
        __syncthreads();

        // ---- h_sum from global (wave-uniform validity); thread (b, kslot) ----
        {
            const int b = tid >> 6, kslot = tid & 63;
            #pragma unroll
            for (int i = 0; i < 2; ++i) {
                const int k = kslot * 4 + i * 256;
                float4 hs = make_float4(0.f, 0.f, 0.f, 0.f);
                #pragma unroll
                for (int c = 0; c < 8; ++c) {
                    const int idx = s_xc[b * 8 + c];
                    if (idx < t) {
                        const float4 v = *(const float4*)&out[((size_t)(b0 + b) * Ln + idx)
                                                              * TWO_M + Mn + k];
                        const float w = s_xmc[b * 8 + c];
                        hs.x += w * v.x; hs.y += w * v.y; hs.z += w * v.z; hs.w += w * v.w;
                    }
                }
                *(float4*)&s_hs[b * 512 + k] = hs;
            }
        }
        // ---- gather c_s (own 16 cols) ----
        if (tid < 256) {
            const int row = tid >> 2, q = tid & 3;
            const int idx = s_xc[row];
            float4 v = make_float4(0.f, 0.f, 0.f, 0.f);
            if (idx < t)
                v = *(const float4*)&out[((size_t)(b0 + (row >> 3)) * Ln + idx) * TWO_M
                                         + m0 + q * 4];
            *(float4*)&s_cs[row * 16 + q * 4] = v;
        }
        __syncthreads();

        // ---- G2: c_h(64 x 512) @ W_fh_slice.T(16), A read direct from L2 ----
        {
            float4 acc2[16];
            #pragma unroll
            for (int rr = 0; rr < 16; ++rr) acc2[rr] = make_float4(0.f, 0.f, 0.f, 0.f);
            #pragma unroll 4
            for (int rr = 0; rr < 16; ++rr) {
                const int row = rq * 16 + rr;
                const int idx = s_xc[row];
                if (idx < t) {   // wave-uniform branch
                    const float* base = &out[((size_t)(b0 + (row >> 3)) * Ln + idx) * TWO_M + Mn];
                    #pragma unroll
                    for (int i4 = 0; i4 < 4; ++i4) {
                        const float4 ch = *(const float4*)&base[ks32 * 4 + i4 * 128];
                        acc2[rr].x += dot4_(ch, w2[0][i4]);
                        acc2[rr].y += dot4_(ch, w2[1][i4]);
                        acc2[rr].z += dot4_(ch, w2[2][i4]);
                        acc2[rr].w += dot4_(ch, w2[3][i4]);
                    }
                }
            }
            #pragma unroll
            for (int rr = 0; rr < 16; ++rr) {
                float4 v = acc2[rr];
                #pragma unroll
                for (int m = 1; m <= 16; m <<= 1) {
                    v.x += __shfl_xor(v.x, m); v.y += __shfl_xor(v.y, m);
                    v.z += __shfl_xor(v.z, m); v.w += __shfl_xor(v.w, m);
                }
                acc2[rr] = v;
            }
            if (ks32 == 0) {
                #pragma unroll
                for (int rr = 0; rr < 16; ++rr)
                    *(float4*)&s_fd[(rq * 16 + rr) * 16 + j4 * 4] = acc2[rr];
            }
        }

        // ---- G1: h_sum(8 x 512) @ W_iouh_slice.T(48); waves 0..5 ----
        if (c8 < 6) {
            float4 a0[8], a1[8];
            #pragma unroll
            for (int b = 0; b < 8; ++b) {
                a0[b] = make_float4(0.f, 0.f, 0.f, 0.f);
                a1[b] = make_float4(0.f, 0.f, 0.f, 0.f);
            }
            #pragma unroll
            for (int b = 0; b < 8; ++b)
                #pragma unroll
                for (int i4 = 0; i4 < 2; ++i4) {
                    const float4 h = *(const float4*)&s_hs[b * 512 + ks64 * 4 + i4 * 256];
                    a0[b].x += dot4_(h, w1[0][i4]); a0[b].y += dot4_(h, w1[1][i4]);
                    a0[b].z += dot4_(h, w1[2][i4]); a0[b].w += dot4_(h, w1[3][i4]);
                    a1[b].x += dot4_(h, w1[4][i4]); a1[b].y += dot4_(h, w1[5][i4]);
                    a1[b].z += dot4_(h, w1[6][i4]); a1[b].w += dot4_(h, w1[7][i4]);
                }
            #pragma unroll
            for (int b = 0; b < 8; ++b) {
                #pragma unroll
                for (int m = 1; m <= 32; m <<= 1) {
                    a0[b].x += __shfl_xor(a0[b].x, m); a0[b].y += __shfl_xor(a0[b].y, m);
                    a0[b].z += __shfl_xor(a0[b].z, m); a0[b].w += __shfl_xor(a0[b].w, m);
                    a1[b].x += __shfl_xor(a1[b].x, m); a1[b].y += __shfl_xor(a1[b].y, m);
                    a1[b].z += __shfl_xor(a1[b].z, m); a1[b].w += __shfl_xor(a1[b].w, m);
                }
            }
            if (ks64 == 0) {
                #pragma unroll
                for (int b = 0; b < 8; ++b) {
                    *(float4*)&s_iou[b * 48 + c8 * 8]     = a0[b];
                    *(float4*)&s_iou[b * 48 + c8 * 8 + 4] = a1[b];
                }
            }
        }
        __syncthreads();

        // ---- gates, c/h, blend vs s_prev, store ----
        if (tid < 128) {
            const int b = tid >> 4, j = tid & 15;
            const float iv = s_iou[b * 48 + j]      + p0;
            const float ov = s_iou[b * 48 + 16 + j] + p1;
            const float uv = s_iou[b * 48 + 32 + j] + p2;
            const float fxv = p3;
            const float i_ = sigmoidf_(iv);
            const float o_ = sigmoidf_(ov);
            const float u_ = tanhf(uv);
            float facc = 0.f;
            #pragma unroll
            for (int c = 0; c < 8; ++c) {
                const int row = b * 8 + c;
                const float f = sigmoidf_(s_fd[row * 16 + j] + bfh_j + fxv);
                facc += f * s_cs[row * 16 + j] * s_xmc[row];
            }
            const float cv = i_ * u_ + facc;
            const float hv = o_ * tanhf(cv);
            const float mv = s_xm[b];
            const float nc = mv * cv + (1.f - mv) * s_prev[b * 32 + j];
            const float nh = mv * hv + (1.f - mv) * s_prev[b * 32 + 16 + j];
            const size_t ob = ((size_t)(b0 + b) * Ln + t) * TWO_M;
            out[ob + m0 + j]      = nc;
            out[ob + Mn + m0 + j] = nh;
            s_prev[b * 32 + j]      = nc;
            s_prev[b * 32 + 16 + j] = nh;
        }
        __syncthreads();

        // ---- group barrier (release writes / acquire before next gather) ----
        if (t < Ln - 1) {
            if (tid == 0) {
                __hip_atomic_fetch_add(myctr, 1u, __ATOMIC_RELEASE, __HIP_MEMORY_SCOPE_AGENT);
                const unsigned target = 32u * (unsigned)t;
                while (__hip_atomic_load(myctr, __ATOMIC_RELAXED, __HIP_MEMORY_SCOPE_AGENT) < target)
                    __builtin_amdgcn_s_sleep(2);
                (void)__hip_atomic_load(myctr, __ATOMIC_ACQUIRE, __HIP_MEMORY_SCOPE_AGENT);
            }
            __syncthreads();
        }
    }
}

// ============================================================================
// Legacy monolithic step kernel (fallback when ws is too small for P)
// ============================================================================
constexpr int LBT = 4, LMT = 32, LNMT = Mn / LMT, LPAD = 4, LDK = Dn + LPAD;
constexpr int L_U16 = 4096, L_CHS = LBT * LDK, L_CH = LBT * Cn * LDK,
              L_WFH = LMT * LDK, L_CS = LBT * Cn * LMT, L_IOUF = 4 * LBT * LMT;
constexpr int L_FLOATS = L_U16 + L_CHS + L_CH + L_WFH + L_CS + L_IOUF + 32 + 4 + 32;
constexpr size_t L_BYTES = (size_t)L_FLOATS * 4;

__global__ __launch_bounds__(256, 1)
void step_legacy(const float* __restrict__ x, const int* __restrict__ x_c,
                 const float* __restrict__ x_m, const float* __restrict__ x_m_c,
                 const float* __restrict__ W_ioux, const float* __restrict__ b_ioux,
                 const float* __restrict__ W_iouh, const float* __restrict__ b_iouh,
                 const float* __restrict__ W_fx, const float* __restrict__ b_fx,
                 const float* __restrict__ W_fh, const float* __restrict__ b_fh,
                 float* __restrict__ out, int t)
{
    extern __shared__ float lds[];
    float* u16    = lds;
    float* s_chs  = u16 + L_U16;
    float* s_ch   = s_chs + L_CHS;
    float* s_wfh  = s_ch + L_CH;
    float* s_cs   = s_wfh + L_WFH;
    float* s_iouf = s_cs + L_CS;
    float* s_xmc  = s_iouf + L_IOUF;
    float* s_xm   = s_xmc + 32;
    int*   s_xc   = (int*)(s_xm + 4);

    const int tid = threadIdx.x;
    const int mt = blockIdx.x & (LNMT - 1);
    const int bt = blockIdx.x >> 4;
    const int b0 = bt * LBT, m0 = mt * LMT;

    #pragma unroll
    for (int i = 0; i < 8; ++i) {
        int flat = i * 256 + tid, b = flat >> 9, k = flat & 511;
        u16[b * LDK + k] = x[((size_t)(b0 + b) * Ln + t) * Dn + k];
    }
    if (tid < 32) {
        int b = tid >> 3, c = tid & 7;
        s_xc[tid]  = x_c[((size_t)(b0 + b) * Ln + t) * Cn + c];
        s_xmc[tid] = x_m_c[((size_t)(b0 + b) * Ln + t) * Cn + c];
    }
    if (tid < 4) s_xm[tid] = x_m[(size_t)(b0 + tid) * Ln + t];
    for (int i = 0; i < 64; ++i) {
        int flat = i * 256 + tid, j = flat >> 9, k = flat & 511;
        s_wfh[j * LDK + k] = W_fh[(size_t)(m0 + j) * Dn + k];
    }
    __syncthreads();

    #pragma unroll
    for (int i = 0; i < 8; ++i) {
        int flat = i * 256 + tid, b = flat >> 9, k = flat & 511;
        float acc = 0.f;
        #pragma unroll
        for (int c = 0; c < 8; ++c) {
            int idx = s_xc[b * 8 + c];
            float v = 0.f;
            if (idx < t) v = out[((size_t)(b0 + b) * Ln + idx) * TWO_M + Mn + k];
            s_ch[(b * 8 + c) * LDK + k] = v;
            acc += s_xmc[b * 8 + c] * v;
        }
        s_chs[b * LDK + k] = acc;
    }
    #pragma unroll
    for (int i = 0; i < 4; ++i) {
        int flat = i * 256 + tid;
        int b = flat >> 8, rem = flat & 255, c = rem >> 5, j = rem & 31;
        int idx = s_xc[b * 8 + c];
        float v = 0.f;
        if (idx < t) v = out[((size_t)(b0 + b) * Ln + idx) * TWO_M + m0 + j];
        s_cs[flat] = v;
    }
    __syncthreads();

    {
        const int unit = tid >> 3, ksl = tid & 7, s = unit >> 3, jg = unit & 7;
        float acc[4][4];
        #pragma unroll
        for (int b = 0; b < 4; ++b)
            #pragma unroll
            for (int jj = 0; jj < 4; ++jj) acc[b][jj] = 0.f;
        if (s < 3) {
            const int colbase = s * Mn + m0 + jg * 4;
            #pragma unroll 4
            for (int it = 0; it < 16; ++it) {
                const int k = it * 32 + ksl * 4;
                float4 sx[4], sc[4];
                #pragma unroll
                for (int b = 0; b < 4; ++b) {
                    sx[b] = *(const float4*)&u16[b * LDK + k];
                    sc[b] = *(const float4*)&s_chs[b * LDK + k];
                }
                #pragma unroll
                for (int jj = 0; jj < 4; ++jj) {
                    const float4 wx = *(const float4*)&W_ioux[(size_t)(colbase + jj) * Dn + k];
                    const float4 wh = *(const float4*)&W_iouh[(size_t)(colbase + jj) * Dn + k];
                    #pragma unroll
                    for (int b = 0; b < 4; ++b)
                        acc[b][jj] += dot4_(sx[b], wx) + dot4_(sc[b], wh);
                }
            }
        } else {
            const int colbase = m0 + jg * 4;
            #pragma unroll 4
            for (int it = 0; it < 16; ++it) {
                const int k = it * 32 + ksl * 4;
                float4 sx[4];
                #pragma unroll
                for (int b = 0; b < 4; ++b) sx[b] = *(const float4*)&u16[b * LDK + k];
                #pragma unroll
                for (int jj = 0; jj < 4; ++jj) {
                    const float4 wx = *(const float4*)&W_fx[(size_t)(colbase + jj) * Dn + k];
                    #pragma unroll
                    for (int b = 0; b < 4; ++b) acc[b][jj] += dot4_(sx[b], wx);
                }
            }
        }
        __syncthreads();
        #pragma unroll
        for (int b = 0; b < 4; ++b)
            #pragma unroll
            for (int jj = 0; jj < 4; ++jj)
                u16[unit * 128 + ksl * 16 + b * 4 + jj] = acc[b][jj];
        __syncthreads();
        #pragma unroll
        for (int e = 0; e < 2; ++e) {
            const int task = e * 256 + tid;
            const int unit2 = task >> 4, rem = task & 15;
            float v = 0.f;
            #pragma unroll
            for (int k2 = 0; k2 < 8; ++k2) v += u16[unit2 * 128 + k2 * 16 + rem];
            const int s2 = unit2 >> 3, jg2 = unit2 & 7;
            const int bb = rem >> 2, jj = rem & 3, j = jg2 * 4 + jj;
            float bias = (s2 < 3) ? (b_ioux[s2 * Mn + m0 + j] + b_iouh[s2 * Mn + m0 + j])
                                  : b_fx[m0 + j];
            s_iouf[(s2 * 4 + bb) * 32 + j] = v + bias;
        }
    }
    __syncthreads();

    {
        const int pos = tid >> 2, ksc = tid & 3, rg = pos >> 3, jg = pos & 7;
        float acc[4][4];
        #pragma unroll
        for (int r = 0; r < 4; ++r)
            #pragma unroll
            for (int j = 0; j < 4; ++j) acc[r][j] = 0.f;
        #pragma unroll 4
        for (int it = 0; it < 32; ++it) {
            const int k = it * 16 + ksc * 4;
            float4 ch[4], wf[4];
            #pragma unroll
            for (int r = 0; r < 4; ++r) ch[r] = *(const float4*)&s_ch[(rg * 4 + r) * LDK + k];
            #pragma unroll
            for (int j = 0; j < 4; ++j) wf[j] = *(const float4*)&s_wfh[(jg * 4 + j) * LDK + k];
            #pragma unroll
            for (int r = 0; r < 4; ++r)
                #pragma unroll
                for (int j = 0; j < 4; ++j) acc[r][j] += dot4_(ch[r], wf[j]);
        }
        #pragma unroll
        for (int r = 0; r < 4; ++r)
            #pragma unroll
            for (int j = 0; j < 4; ++j)
                u16[((rg * 4 + r) * 32 + (jg * 4 + j)) * 4 + ksc] = acc[r][j];
    }
    __syncthreads();

    if (tid < 128) {
        const int b = tid >> 5, j = tid & 31;
        const float iv  = s_iouf[(0 * 4 + b) * 32 + j];
        const float ov  = s_iouf[(1 * 4 + b) * 32 + j];
        const float uv  = s_iouf[(2 * 4 + b) * 32 + j];
        const float fxv = s_iouf[(3 * 4 + b) * 32 + j];
        const float i_ = sigmoidf_(iv), o_ = sigmoidf_(ov), u_ = tanhf(uv);
        const float bfh = b_fh[m0 + j];
        float facc = 0.f;
        #pragma unroll
        for (int c = 0; c < 8; ++c) {
            const int row = b * 8 + c;
            const float fd = u16[(row * 32 + j) * 4 + 0] + u16[(row * 32 + j) * 4 + 1]
                           + u16[(row * 32 + j) * 4 + 2] + u16[(row * 32 + j) * 4 + 3];
            const float f = sigmoidf_(fd + bfh + fxv);
            facc += f * s_cs[row * 32 + j] * s_xmc[row];
        }
        const float cval = i_ * u_ + facc;
        const float hval = o_ * tanhf(cval);
        const float mval = s_xm[b];
        const size_t base  = ((size_t)(b0 + b) * Ln + t) * TWO_M;
        const size_t pbase = ((size_t)(b0 + b) * Ln + (t - 1)) * TWO_M;
        out[base + m0 + j]      = mval * cval + (1.f - mval) * out[pbase + m0 + j];
        out[base + Mn + m0 + j] = mval * hval + (1.f - mval) * out[pbase + Mn + m0 + j];
    }
}

__global__ void zero_row0(float* __restrict__ out) {
    int i = blockIdx.x * 256 + threadIdx.x;
    int b = i >> 10, j = i & 1023;
    out[(size_t)b * Ln * TWO_M + j] = 0.f;
}

__global__ void zero_ctr(unsigned* __restrict__ c) {
    if (threadIdx.x < 8) c[threadIdx.x * 32] = 0u;
}

__global__ void final_copy(const float* __restrict__ out, float* __restrict__ fin) {
    int i = blockIdx.x * 256 + threadIdx.x;
    int b = i >> 10, j = i & 1023;
    fin[i] = out[((size_t)b * Ln + (Ln - 1)) * TWO_M + j];
}

} // namespace

extern "C" void kernel_launch(void* const* d_in, const int* in_sizes, int n_in,
                              void* d_out, int out_size, void* d_ws, size_t ws_size,
                              hipStream_t stream) {
    (void)in_sizes; (void)n_in; (void)out_size;
    const float* x      = (const float*)d_in[0];
    const int*   x_c    = (const int*)d_in[1];
    const float* x_m    = (const float*)d_in[2];
    const float* x_m_c  = (const float*)d_in[3];
    const float* W_ioux = (const float*)d_in[4];
    const float* b_ioux = (const float*)d_in[5];
    const float* W_iouh = (const float*)d_in[6];
    const float* b_iouh = (const float*)d_in[7];
    const float* W_fx   = (const float*)d_in[8];
    const float* b_fx   = (const float*)d_in[9];
    const float* W_fh   = (const float*)d_in[10];
    const float* b_fh   = (const float*)d_in[11];
    float* out = (float*)d_out;
    float* fin = out + (size_t)Bn * Ln * TWO_M;

    hipFuncSetAttribute((const void*)step_legacy,
                        hipFuncAttributeMaxDynamicSharedMemorySize, (int)L_BYTES);

    hipLaunchKernelGGL(zero_row0, dim3(256), dim3(256), 0, stream, out);

    if (ws_size >= P_BYTES) {
        float* Pp = (float*)d_ws;
        // barrier counters overlap P row (b=0,t=0), which no step reads.
        unsigned* ctr = (unsigned*)d_ws;
        hipLaunchKernelGGL(proj2_kernel, dim3(8192), dim3(256), 0, stream,
                           x, W_ioux, b_ioux, b_iouh, W_fx, b_fx, Pp);
        hipLaunchKernelGGL(zero_ctr, dim3(1), dim3(64), 0, stream, ctr);
        void* kargs[] = { (void*)&x_c, (void*)&x_m, (void*)&x_m_c, (void*)&W_iouh,
                          (void*)&W_fh, (void*)&b_fh, (void*)&Pp, (void*)&out,
                          (void*)&ctr };
        hipLaunchCooperativeKernel((const void*)persist2_kernel, dim3(256), dim3(512),
                                   kargs, 0, stream);
    } else {
        for (int t = 1; t < Ln; ++t) {
            hipLaunchKernelGGL(step_legacy, dim3(256), dim3(256), L_BYTES, stream,
                               x, x_c, x_m, x_m_c, W_ioux, b_ioux, W_iouh, b_iouh,
                               W_fx, b_fx, W_fh, b_fh, out, t);
        }
    }
    hipLaunchKernelGGL(final_copy, dim3(256), dim3(256), 0, stream, out, fin);
}

// Round 5
// 5129.662 us; speedup vs baseline: 3.0331x; 2.8759x over previous
//
#include <hip/hip_runtime.h>
#include <math.h>

namespace {

constexpr int Bn = 64, Ln = 256, Cn = 8, Dn = 512, Mn = 512;
constexpr int TWO_M = 2 * Mn;        // 1024
constexpr int PCOLS = 2048;          // 1536 iou (+both biases) | 512 fx (+b_fx)
constexpr size_t P_FLOATS = (size_t)Bn * Ln * PCOLS;   // 33,554,432
constexpr size_t P_BYTES  = P_FLOATS * 4;              // 128 MB

__device__ __forceinline__ float sigmoidf_(float v) { return 1.0f / (1.0f + __expf(-v)); }
__device__ __forceinline__ float dot4_(float4 a, float4 b) {
    return a.x * b.x + a.y * b.y + a.z * b.z + a.w * b.w;
}

// ============================================================================
// proj2: P[r][0:1536] = x_r @ W_ioux.T + b_ioux + b_iouh
//        P[r][1536:2048] = x_r @ W_fx.T + b_fx        (r = b*Ln + t)
// ============================================================================
constexpr int PJLD = 36;

__global__ __launch_bounds__(256)
void proj2_kernel(const float* __restrict__ x,
                  const float* __restrict__ W_ioux, const float* __restrict__ b_ioux,
                  const float* __restrict__ b_iouh,
                  const float* __restrict__ W_fx, const float* __restrict__ b_fx,
                  float* __restrict__ P)
{
    __shared__ float sA[64 * PJLD];
    __shared__ float sB[64 * PJLD];
    const int tid = threadIdx.x;
    const int rb = blockIdx.x >> 5;       // 0..255
    const int cb = blockIdx.x & 31;       // 0..31
    const int r0 = rb * 64, c0 = cb * 64;
    const bool is_iou = (c0 < 3 * Mn);
    const int ri = tid & 15, ci = tid >> 4;

    float acc[4][4];
    #pragma unroll
    for (int r = 0; r < 4; ++r)
        #pragma unroll
        for (int c = 0; c < 4; ++c) acc[r][c] = 0.f;

    for (int k0 = 0; k0 < Dn; k0 += 32) {
        #pragma unroll
        for (int i = 0; i < 2; ++i) {
            const int flat = i * 256 + tid;           // 0..511
            const int row = flat >> 3, kq = flat & 7;
            *(float4*)&sA[row * PJLD + kq * 4] =
                *(const float4*)&x[(size_t)(r0 + row) * Dn + k0 + kq * 4];
            const float* wsrc = is_iou ? &W_ioux[(size_t)(c0 + row) * Dn]
                                       : &W_fx[(size_t)(c0 - 3 * Mn + row) * Dn];
            *(float4*)&sB[row * PJLD + kq * 4] = *(const float4*)&wsrc[k0 + kq * 4];
        }
        __syncthreads();
        #pragma unroll
        for (int k4 = 0; k4 < 8; ++k4) {
            float4 av[4], bv[4];
            #pragma unroll
            for (int r = 0; r < 4; ++r) av[r] = *(const float4*)&sA[(ri + r * 16) * PJLD + k4 * 4];
            #pragma unroll
            for (int c = 0; c < 4; ++c) bv[c] = *(const float4*)&sB[(ci + c * 16) * PJLD + k4 * 4];
            #pragma unroll
            for (int r = 0; r < 4; ++r)
                #pragma unroll
                for (int c = 0; c < 4; ++c) acc[r][c] += dot4_(av[r], bv[c]);
        }
        __syncthreads();
    }
    #pragma unroll
    for (int c = 0; c < 4; ++c) {
        const int col = c0 + ci + c * 16;
        const float bias = is_iou ? (b_ioux[col] + b_iouh[col]) : b_fx[col - 3 * Mn];
        #pragma unroll
        for (int r = 0; r < 4; ++r)
            P[(size_t)(r0 + ri + r * 16) * PCOLS + col] = acc[r][c] + bias;
    }
}

// ============================================================================
// persist3: 256 blocks = 8 groups (bid&7, XCD-co-located) x 32 m-blocks.
// Weights live in LDS for the whole kernel (immune to per-step L2 inv, no
// VGPR spill). Gathers are unguarded: invalid child idx redirects to row 0,
// which is zeroed (matches reference semantics exactly).
// LDS layouts pre-swizzled at load so hot ds_read_b128 are conflict-free.
// ============================================================================
// LDS carve (floats)
constexpr int PW2 = 0;                   // W_fh slice  [i(16)][col(16)][9 f4 pad]
constexpr int PW2_SZ = 16 * 16 * 9 * 4;  // 9216
constexpr int PW1 = PW2 + PW2_SZ;        // W_iouh slice [i(16)][cc(2)][192 f4]
constexpr int PW1_SZ = 16 * 2 * 192 * 4; // 24576
constexpr int PHS = PW1 + PW1_SZ;        // h_sum 8x512          = 4096
constexpr int PFD = PHS + 4096;          // G2 out 64x16         = 1024
constexpr int PIO = PFD + 1024;          // G1 out 8x48          = 384
constexpr int PCS = PIO + 384;           // c_s 64x16            = 1024
constexpr int PPV = PCS + 1024;          // prev state 8x32      = 256
constexpr int PXMC = PPV + 256;          // 64
constexpr int PXM = PXMC + 64;           // 8
constexpr int PXC = PXM + 8;             // 64 (ints)
constexpr int P_LDS_FLOATS = PXC + 64;   // 40712
constexpr size_t P_LDS_BYTES = (size_t)P_LDS_FLOATS * 4;   // 162,848
static_assert(P_LDS_BYTES <= 163840, "persist3 LDS over budget");

__global__ __launch_bounds__(512, 2)
void persist3_kernel(const int* __restrict__ x_c, const float* __restrict__ x_m,
                     const float* __restrict__ x_m_c,
                     const float* __restrict__ W_iouh, const float* __restrict__ W_fh,
                     const float* __restrict__ b_fh, const float* __restrict__ P,
                     float* __restrict__ out, unsigned* __restrict__ ctr)
{
    extern __shared__ float lds[];
    float* w2   = lds + PW2;
    float* w1   = lds + PW1;
    float* s_hs = lds + PHS;
    float* s_fd = lds + PFD;
    float* s_io = lds + PIO;
    float* s_cs = lds + PCS;
    float* s_pv = lds + PPV;
    float* s_xmc = lds + PXMC;
    float* s_xm  = lds + PXM;
    int*   s_xc  = (int*)(lds + PXC);

    const int tid = threadIdx.x;
    const int g  = blockIdx.x & 7;        // group varies fastest -> XCD co-location
    const int mt = blockIdx.x >> 3;       // 0..31
    const int m0 = mt * 16;
    const int b0 = g * 8;
    unsigned* myctr = ctr + g * 32;       // 128B-separated counters

    // ---- one-time: stage weight slices into LDS with swizzled layouts ----
    #pragma unroll
    for (int chk = 0; chk < 4; ++chk) {
        const int q = chk * 512 + tid;              // f4 id 0..2047
        const int i = q >> 7, col = (q >> 3) & 15, ks = q & 7;
        *(float4*)&w2[(i * 144 + col * 9 + ks) * 4] =
            *(const float4*)&W_fh[(size_t)(m0 + col) * Dn + ks * 4 + i * 32];
    }
    #pragma unroll
    for (int chk = 0; chk < 12; ++chk) {
        const int q = chk * 512 + tid;              // f4 id 0..6143
        const int i = q / 384, r1 = q % 384;
        const int cc = r1 / 192, m = r1 % 192;
        const int cq = m >> 3, ks = m & 7;
        const int c = cq * 2 + cc, s = c >> 4, j = c & 15;
        *(float4*)&w1[q * 4] =
            *(const float4*)&W_iouh[(size_t)(s * Mn + m0 + j) * Mn + ks * 4 + i * 32];
    }
    const float bfh_j = b_fh[m0 + (tid & 15)];
    if (tid < 256) s_pv[tid] = 0.f;

    // thread mappings
    const int g2_rq = tid >> 5, g2_jh = (tid >> 3) & 3, g2_ks = tid & 7;  // rows 4, cols 4, ks8
    const int g1_bq = tid / 192, g1_r = tid % 192;
    const int g1_cq = g1_r >> 3, g1_ks = g1_r & 7;                        // b 4, cols 2, ks8
    const int p1_b = tid >> 6, p1_k = tid & 63;
    __syncthreads();

    for (int t = 1; t < Ln; ++t) {
        // ---- early P prefetch (latency hidden under whole step) ----
        float p0 = 0.f, p1 = 0.f, p2 = 0.f, p3 = 0.f;
        if (tid < 128) {
            const size_t prow = ((size_t)(b0 + (tid >> 4)) * Ln + t) * (size_t)PCOLS
                                + m0 + (tid & 15);
            p0 = P[prow];           p1 = P[prow + Mn];
            p2 = P[prow + 2 * Mn];  p3 = P[prow + 3 * Mn];
        }
        // ---- per-step scalars; invalid children redirect to zeroed row 0 ----
        if (tid < 64) {
            const int b = tid >> 3, c = tid & 7;
            const int idx = x_c[((size_t)(b0 + b) * Ln + t) * Cn + c];
            s_xc[tid]  = (idx < t) ? idx : 0;
            s_xmc[tid] = x_m_c[((size_t)(b0 + b) * Ln + t) * Cn + c];
        } else if (tid < 72) {
            s_xm[tid - 64] = x_m[(size_t)(b0 + tid - 64) * Ln + t];
        }
        __syncthreads();

        // ---- pass1: h_sum (wave = one batch, contiguous k) ----
        {
            const float* rowp[8];
            float wt[8];
            #pragma unroll
            for (int c = 0; c < 8; ++c) {
                rowp[c] = &out[((size_t)(b0 + p1_b) * Ln + s_xc[p1_b * 8 + c]) * TWO_M + Mn];
                wt[c] = s_xmc[p1_b * 8 + c];
            }
            #pragma unroll
            for (int i = 0; i < 2; ++i) {
                const int k = p1_k * 4 + i * 256;
                float4 hs = make_float4(0.f, 0.f, 0.f, 0.f);
                #pragma unroll
                for (int c = 0; c < 8; ++c) {
                    const float4 v = *(const float4*)&rowp[c][k];
                    hs.x += wt[c] * v.x; hs.y += wt[c] * v.y;
                    hs.z += wt[c] * v.z; hs.w += wt[c] * v.w;
                }
                *(float4*)&s_hs[p1_b * 512 + k] = hs;
            }
        }
        // ---- c_s gather (own 16 cols) ----
        if (tid < 256) {
            const int row = tid >> 2, q = tid & 3;
            const float4 v = *(const float4*)&out[((size_t)(b0 + (row >> 3)) * Ln
                                                   + s_xc[row]) * TWO_M + m0 + q * 4];
            *(float4*)&s_cs[row * 16 + q * 4] = v;
        }
        __syncthreads();

        // ---- G2: c_h(64x512) @ W_fh_slice.T(16); acc 4 rows x 4 cols, ks8 ----
        {
            const float* rp[4];
            #pragma unroll
            for (int r = 0; r < 4; ++r) {
                const int row = g2_rq * 4 + r;
                rp[r] = &out[((size_t)(b0 + (row >> 3)) * Ln + s_xc[row]) * TWO_M + Mn];
            }
            float acc[4][4];
            #pragma unroll
            for (int r = 0; r < 4; ++r)
                #pragma unroll
                for (int jj = 0; jj < 4; ++jj) acc[r][jj] = 0.f;
            #pragma unroll 4
            for (int i = 0; i < 16; ++i) {
                const int k = g2_ks * 4 + i * 32;
                float4 cv[4], wv[4];
                #pragma unroll
                for (int r = 0; r < 4; ++r) cv[r] = *(const float4*)&rp[r][k];
                #pragma unroll
                for (int jj = 0; jj < 4; ++jj)
                    wv[jj] = *(const float4*)&w2[(i * 144 + (g2_jh * 4 + jj) * 9 + g2_ks) * 4];
                #pragma unroll
                for (int r = 0; r < 4; ++r)
                    #pragma unroll
                    for (int jj = 0; jj < 4; ++jj) acc[r][jj] += dot4_(cv[r], wv[jj]);
            }
            #pragma unroll
            for (int r = 0; r < 4; ++r)
                #pragma unroll
                for (int jj = 0; jj < 4; ++jj) {
                    float v = acc[r][jj];
                    v += __shfl_xor(v, 1); v += __shfl_xor(v, 2); v += __shfl_xor(v, 4);
                    acc[r][jj] = v;
                }
            if (g2_ks == 0) {
                #pragma unroll
                for (int r = 0; r < 4; ++r)
                    *(float4*)&s_fd[(g2_rq * 4 + r) * 16 + g2_jh * 4] =
                        make_float4(acc[r][0], acc[r][1], acc[r][2], acc[r][3]);
            }
        }
        // ---- G1: h_sum(8x512) @ W_iouh_slice.T(48); acc 4 b x 2 cols, ks8 ----
        if (tid < 384) {
            float acc[2][4];
            #pragma unroll
            for (int cc = 0; cc < 2; ++cc)
                #pragma unroll
                for (int bb = 0; bb < 4; ++bb) acc[cc][bb] = 0.f;
            #pragma unroll 4
            for (int i = 0; i < 16; ++i) {
                const int k = g1_ks * 4 + i * 32;
                float4 hv[4];
                #pragma unroll
                for (int bb = 0; bb < 4; ++bb)
                    hv[bb] = *(const float4*)&s_hs[(g1_bq * 4 + bb) * 512 + k];
                #pragma unroll
                for (int cc = 0; cc < 2; ++cc) {
                    const float4 wv = *(const float4*)&w1[((i * 2 + cc) * 192
                                                           + g1_cq * 8 + g1_ks) * 4];
                    #pragma unroll
                    for (int bb = 0; bb < 4; ++bb) acc[cc][bb] += dot4_(hv[bb], wv);
                }
            }
            #pragma unroll
            for (int cc = 0; cc < 2; ++cc)
                #pragma unroll
                for (int bb = 0; bb < 4; ++bb) {
                    float v = acc[cc][bb];
                    v += __shfl_xor(v, 1); v += __shfl_xor(v, 2); v += __shfl_xor(v, 4);
                    acc[cc][bb] = v;
                }
            if (g1_ks == 0) {
                #pragma unroll
                for (int cc = 0; cc < 2; ++cc)
                    #pragma unroll
                    for (int bb = 0; bb < 4; ++bb)
                        s_io[(g1_bq * 4 + bb) * 48 + g1_cq * 2 + cc] = acc[cc][bb];
            }
        }
        __syncthreads();

        // ---- gates, c/h, blend vs s_pv, store ----
        if (tid < 128) {
            const int b = tid >> 4, j = tid & 15;
            const float iv = s_io[b * 48 + j]      + p0;
            const float ov = s_io[b * 48 + 16 + j] + p1;
            const float uv = s_io[b * 48 + 32 + j] + p2;
            const float i_ = sigmoidf_(iv);
            const float o_ = sigmoidf_(ov);
            const float u_ = tanhf(uv);
            float facc = 0.f;
            #pragma unroll
            for (int c = 0; c < 8; ++c) {
                const int row = b * 8 + c;
                const float f = sigmoidf_(s_fd[row * 16 + j] + bfh_j + p3);
                facc += f * s_cs[row * 16 + j] * s_xmc[row];
            }
            const float cv = i_ * u_ + facc;
            const float hv = o_ * tanhf(cv);
            const float mv = s_xm[b];
            const float nc = mv * cv + (1.f - mv) * s_pv[b * 32 + j];
            const float nh = mv * hv + (1.f - mv) * s_pv[b * 32 + 16 + j];
            const size_t ob = ((size_t)(b0 + b) * Ln + t) * TWO_M;
            out[ob + m0 + j]      = nc;
            out[ob + Mn + m0 + j] = nh;
            s_pv[b * 32 + j]      = nc;
            s_pv[b * 32 + 16 + j] = nh;
        }
        __syncthreads();

        // ---- group barrier (release writes / acquire before next gather) ----
        if (t < Ln - 1) {
            if (tid == 0) {
                __hip_atomic_fetch_add(myctr, 1u, __ATOMIC_RELEASE, __HIP_MEMORY_SCOPE_AGENT);
                const unsigned target = 32u * (unsigned)t;
                while (__hip_atomic_load(myctr, __ATOMIC_RELAXED, __HIP_MEMORY_SCOPE_AGENT) < target)
                    __builtin_amdgcn_s_sleep(2);
                (void)__hip_atomic_load(myctr, __ATOMIC_ACQUIRE, __HIP_MEMORY_SCOPE_AGENT);
            }
            __syncthreads();
        }
    }
}

// ============================================================================
// Legacy monolithic step kernel (fallback when ws is too small for P)
// ============================================================================
constexpr int LBT = 4, LMT = 32, LNMT = Mn / LMT, LPAD = 4, LDK = Dn + LPAD;
constexpr int L_U16 = 4096, L_CHS = LBT * LDK, L_CH = LBT * Cn * LDK,
              L_WFH = LMT * LDK, L_CS = LBT * Cn * LMT, L_IOUF = 4 * LBT * LMT;
constexpr int L_FLOATS = L_U16 + L_CHS + L_CH + L_WFH + L_CS + L_IOUF + 32 + 4 + 32;
constexpr size_t L_BYTES = (size_t)L_FLOATS * 4;

__global__ __launch_bounds__(256, 1)
void step_legacy(const float* __restrict__ x, const int* __restrict__ x_c,
                 const float* __restrict__ x_m, const float* __restrict__ x_m_c,
                 const float* __restrict__ W_ioux, const float* __restrict__ b_ioux,
                 const float* __restrict__ W_iouh, const float* __restrict__ b_iouh,
                 const float* __restrict__ W_fx, const float* __restrict__ b_fx,
                 const float* __restrict__ W_fh, const float* __restrict__ b_fh,
                 float* __restrict__ out, int t)
{
    extern __shared__ float lds[];
    float* u16    = lds;
    float* s_chs  = u16 + L_U16;
    float* s_ch   = s_chs + L_CHS;
    float* s_wfh  = s_ch + L_CH;
    float* s_cs   = s_wfh + L_WFH;
    float* s_iouf = s_cs + L_CS;
    float* s_xmc  = s_iouf + L_IOUF;
    float* s_xm   = s_xmc + 32;
    int*   s_xc   = (int*)(s_xm + 4);

    const int tid = threadIdx.x;
    const int mt = blockIdx.x & (LNMT - 1);
    const int bt = blockIdx.x >> 4;
    const int b0 = bt * LBT, m0 = mt * LMT;

    #pragma unroll
    for (int i = 0; i < 8; ++i) {
        int flat = i * 256 + tid, b = flat >> 9, k = flat & 511;
        u16[b * LDK + k] = x[((size_t)(b0 + b) * Ln + t) * Dn + k];
    }
    if (tid < 32) {
        int b = tid >> 3, c = tid & 7;
        s_xc[tid]  = x_c[((size_t)(b0 + b) * Ln + t) * Cn + c];
        s_xmc[tid] = x_m_c[((size_t)(b0 + b) * Ln + t) * Cn + c];
    }
    if (tid < 4) s_xm[tid] = x_m[(size_t)(b0 + tid) * Ln + t];
    for (int i = 0; i < 64; ++i) {
        int flat = i * 256 + tid, j = flat >> 9, k = flat & 511;
        s_wfh[j * LDK + k] = W_fh[(size_t)(m0 + j) * Dn + k];
    }
    __syncthreads();

    #pragma unroll
    for (int i = 0; i < 8; ++i) {
        int flat = i * 256 + tid, b = flat >> 9, k = flat & 511;
        float acc = 0.f;
        #pragma unroll
        for (int c = 0; c < 8; ++c) {
            int idx = s_xc[b * 8 + c];
            float v = 0.f;
            if (idx < t) v = out[((size_t)(b0 + b) * Ln + idx) * TWO_M + Mn + k];
            s_ch[(b * 8 + c) * LDK + k] = v;
            acc += s_xmc[b * 8 + c] * v;
        }
        s_chs[b * LDK + k] = acc;
    }
    #pragma unroll
    for (int i = 0; i < 4; ++i) {
        int flat = i * 256 + tid;
        int b = flat >> 8, rem = flat & 255, c = rem >> 5, j = rem & 31;
        int idx = s_xc[b * 8 + c];
        float v = 0.f;
        if (idx < t) v = out[((size_t)(b0 + b) * Ln + idx) * TWO_M + m0 + j];
        s_cs[flat] = v;
    }
    __syncthreads();

    {
        const int unit = tid >> 3, ksl = tid & 7, s = unit >> 3, jg = unit & 7;
        float acc[4][4];
        #pragma unroll
        for (int b = 0; b < 4; ++b)
            #pragma unroll
            for (int jj = 0; jj < 4; ++jj) acc[b][jj] = 0.f;
        if (s < 3) {
            const int colbase = s * Mn + m0 + jg * 4;
            #pragma unroll 4
            for (int it = 0; it < 16; ++it) {
                const int k = it * 32 + ksl * 4;
                float4 sx[4], sc[4];
                #pragma unroll
                for (int b = 0; b < 4; ++b) {
                    sx[b] = *(const float4*)&u16[b * LDK + k];
                    sc[b] = *(const float4*)&s_chs[b * LDK + k];
                }
                #pragma unroll
                for (int jj = 0; jj < 4; ++jj) {
                    const float4 wx = *(const float4*)&W_ioux[(size_t)(colbase + jj) * Dn + k];
                    const float4 wh = *(const float4*)&W_iouh[(size_t)(colbase + jj) * Dn + k];
                    #pragma unroll
                    for (int b = 0; b < 4; ++b)
                        acc[b][jj] += dot4_(sx[b], wx) + dot4_(sc[b], wh);
                }
            }
        } else {
            const int colbase = m0 + jg * 4;
            #pragma unroll 4
            for (int it = 0; it < 16; ++it) {
                const int k = it * 32 + ksl * 4;
                float4 sx[4];
                #pragma unroll
                for (int b = 0; b < 4; ++b) sx[b] = *(const float4*)&u16[b * LDK + k];
                #pragma unroll
                for (int jj = 0; jj < 4; ++jj) {
                    const float4 wx = *(const float4*)&W_fx[(size_t)(colbase + jj) * Dn + k];
                    #pragma unroll
                    for (int b = 0; b < 4; ++b) acc[b][jj] += dot4_(sx[b], wx);
                }
            }
        }
        __syncthreads();
        #pragma unroll
        for (int b = 0; b < 4; ++b)
            #pragma unroll
            for (int jj = 0; jj < 4; ++jj)
                u16[unit * 128 + ksl * 16 + b * 4 + jj] = acc[b][jj];
        __syncthreads();
        #pragma unroll
        for (int e = 0; e < 2; ++e) {
            const int task = e * 256 + tid;
            const int unit2 = task >> 4, rem = task & 15;
            float v = 0.f;
            #pragma unroll
            for (int k2 = 0; k2 < 8; ++k2) v += u16[unit2 * 128 + k2 * 16 + rem];
            const int s2 = unit2 >> 3, jg2 = unit2 & 7;
            const int bb = rem >> 2, jj = rem & 3, j = jg2 * 4 + jj;
            float bias = (s2 < 3) ? (b_ioux[s2 * Mn + m0 + j] + b_iouh[s2 * Mn + m0 + j])
                                  : b_fx[m0 + j];
            s_iouf[(s2 * 4 + bb) * 32 + j] = v + bias;
        }
    }
    __syncthreads();

    {
        const int pos = tid >> 2, ksc = tid & 3, rg = pos >> 3, jg = pos & 7;
        float acc[4][4];
        #pragma unroll
        for (int r = 0; r < 4; ++r)
            #pragma unroll
            for (int j = 0; j < 4; ++j) acc[r][j] = 0.f;
        #pragma unroll 4
        for (int it = 0; it < 32; ++it) {
            const int k = it * 16 + ksc * 4;
            float4 ch[4], wf[4];
            #pragma unroll
            for (int r = 0; r < 4; ++r) ch[r] = *(const float4*)&s_ch[(rg * 4 + r) * LDK + k];
            #pragma unroll
            for (int j = 0; j < 4; ++j) wf[j] = *(const float4*)&s_wfh[(jg * 4 + j) * LDK + k];
            #pragma unroll
            for (int r = 0; r < 4; ++r)
                #pragma unroll
                for (int j = 0; j < 4; ++j) acc[r][j] += dot4_(ch[r], wf[j]);
        }
        #pragma unroll
        for (int r = 0; r < 4; ++r)
            #pragma unroll
            for (int j = 0; j < 4; ++j)
                u16[((rg * 4 + r) * 32 + (jg * 4 + j)) * 4 + ksc] = acc[r][j];
    }
    __syncthreads();

    if (tid < 128) {
        const int b = tid >> 5, j = tid & 31;
        const float iv  = s_iouf[(0 * 4 + b) * 32 + j];
        const float ov  = s_iouf[(1 * 4 + b) * 32 + j];
        const float uv  = s_iouf[(2 * 4 + b) * 32 + j];
        const float fxv = s_iouf[(3 * 4 + b) * 32 + j];
        const float i_ = sigmoidf_(iv), o_ = sigmoidf_(ov), u_ = tanhf(uv);
        const float bfh = b_fh[m0 + j];
        float facc = 0.f;
        #pragma unroll
        for (int c = 0; c < 8; ++c) {
            const int row = b * 8 + c;
            const float fd = u16[(row * 32 + j) * 4 + 0] + u16[(row * 32 + j) * 4 + 1]
                           + u16[(row * 32 + j) * 4 + 2] + u16[(row * 32 + j) * 4 + 3];
            const float f = sigmoidf_(fd + bfh + fxv);
            facc += f * s_cs[row * 32 + j] * s_xmc[row];
        }
        const float cval = i_ * u_ + facc;
        const float hval = o_ * tanhf(cval);
        const float mval = s_xm[b];
        const size_t base  = ((size_t)(b0 + b) * Ln + t) * TWO_M;
        const size_t pbase = ((size_t)(b0 + b) * Ln + (t - 1)) * TWO_M;
        out[base + m0 + j]      = mval * cval + (1.f - mval) * out[pbase + m0 + j];
        out[base + Mn + m0 + j] = mval * hval + (1.f - mval) * out[pbase + Mn + m0 + j];
    }
}

__global__ void zero_row0(float* __restrict__ out) {
    int i = blockIdx.x * 256 + threadIdx.x;
    int b = i >> 10, j = i & 1023;
    out[(size_t)b * Ln * TWO_M + j] = 0.f;
}

__global__ void zero_ctr(unsigned* __restrict__ c) {
    if (threadIdx.x < 8) c[threadIdx.x * 32] = 0u;
}

__global__ void final_copy(const float* __restrict__ out, float* __restrict__ fin) {
    int i = blockIdx.x * 256 + threadIdx.x;
    int b = i >> 10, j = i & 1023;
    fin[i] = out[((size_t)b * Ln + (Ln - 1)) * TWO_M + j];
}

} // namespace

extern "C" void kernel_launch(void* const* d_in, const int* in_sizes, int n_in,
                              void* d_out, int out_size, void* d_ws, size_t ws_size,
                              hipStream_t stream) {
    (void)in_sizes; (void)n_in; (void)out_size;
    const float* x      = (const float*)d_in[0];
    const int*   x_c    = (const int*)d_in[1];
    const float* x_m    = (const float*)d_in[2];
    const float* x_m_c  = (const float*)d_in[3];
    const float* W_ioux = (const float*)d_in[4];
    const float* b_ioux = (const float*)d_in[5];
    const float* W_iouh = (const float*)d_in[6];
    const float* b_iouh = (const float*)d_in[7];
    const float* W_fx   = (const float*)d_in[8];
    const float* b_fx   = (const float*)d_in[9];
    const float* W_fh   = (const float*)d_in[10];
    const float* b_fh   = (const float*)d_in[11];
    float* out = (float*)d_out;
    float* fin = out + (size_t)Bn * Ln * TWO_M;

    hipFuncSetAttribute((const void*)persist3_kernel,
                        hipFuncAttributeMaxDynamicSharedMemorySize, (int)P_LDS_BYTES);
    hipFuncSetAttribute((const void*)step_legacy,
                        hipFuncAttributeMaxDynamicSharedMemorySize, (int)L_BYTES);

    hipLaunchKernelGGL(zero_row0, dim3(256), dim3(256), 0, stream, out);

    if (ws_size >= P_BYTES) {
        float* Pp = (float*)d_ws;
        // barrier counters overlap P row (b=0,t=0), which no step reads.
        unsigned* ctr = (unsigned*)d_ws;
        hipLaunchKernelGGL(proj2_kernel, dim3(8192), dim3(256), 0, stream,
                           x, W_ioux, b_ioux, b_iouh, W_fx, b_fx, Pp);
        hipLaunchKernelGGL(zero_ctr, dim3(1), dim3(64), 0, stream, ctr);
        void* kargs[] = { (void*)&x_c, (void*)&x_m, (void*)&x_m_c, (void*)&W_iouh,
                          (void*)&W_fh, (void*)&b_fh, (void*)&Pp, (void*)&out,
                          (void*)&ctr };
        hipLaunchCooperativeKernel((const void*)persist3_kernel, dim3(256), dim3(512),
                                   kargs, (unsigned)P_LDS_BYTES, stream);
    } else {
        for (int t = 1; t < Ln; ++t) {
            hipLaunchKernelGGL(step_legacy, dim3(256), dim3(256), L_BYTES, stream,
                               x, x_c, x_m, x_m_c, W_ioux, b_ioux, W_iouh, b_iouh,
                               W_fx, b_fx, W_fh, b_fh, out, t);
        }
    }
    hipLaunchKernelGGL(final_copy, dim3(256), dim3(256), 0, stream, out, fin);
}